// Round 16
// baseline (151.145 us; speedup 1.0000x reference)
//
#include <hip/hip_runtime.h>

#define DIM 256
#define NH 8
#define HE 32          // head dim E
#define BALL 16        // ball size M
#define NBALLS 512
#define NM 8192

typedef _Float16 f16x8 __attribute__((ext_vector_type(8)));
typedef _Float16 f16x2 __attribute__((ext_vector_type(2)));
typedef float f32x4 __attribute__((ext_vector_type(4)));

#if __has_builtin(__builtin_amdgcn_fdot2)
#define FDOT2(a, b, c) __builtin_amdgcn_fdot2((a), (b), (c), false)
#else
#define FDOT2(a, b, c) \
  ((c) + (float)(a)[0] * (float)(b)[0] + (float)(a)[1] * (float)(b)[1])
#endif

// fp16 2-term split: x = hi + lo, residual ~2^-24 |x| (fp32-quality)
__device__ __forceinline__ void f2h_split(float val, _Float16& hi,
                                          _Float16& lo) {
  hi = (_Float16)val;
  lo = (_Float16)(val - (float)hi);
}

// async global->LDS, 16B per lane; LDS dest = wave-uniform base + lane*16
__device__ __forceinline__ void gld_lds16(_Float16* lds, const _Float16* g) {
  __builtin_amdgcn_global_load_lds(
      (const __attribute__((address_space(1))) unsigned int*)g,
      (__attribute__((address_space(3))) unsigned int*)lds, 16, 0, 0);
}

// ---------------------------------------------------------------------------
// K1 (fused): blocks [0,512): posembed -> xcat[t][hi256|lo256]
//   blocks [512,1536): weight split -> Bq/Bp concatenated-K fp16.
//   Bq rows PERMUTED component-major: row n' = c*256 + h*32 + e.
// ---------------------------------------------------------------------------
__global__ __launch_bounds__(256) void k_prep(
    const float* __restrict__ x, const float* __restrict__ pos,
    const float* __restrict__ Wpe, const float* __restrict__ bpe,
    _Float16* __restrict__ xcat, const float* __restrict__ Wq,
    const float* __restrict__ Wp, _Float16* __restrict__ Bq,
    _Float16* __restrict__ Bp) {
  if (blockIdx.x >= NBALLS) {
    int n = blockIdx.x - NBALLS;  // 0..1023
    int k = threadIdx.x;
    if (n < 768) {
      int c = n % 3, rr = n / 3;
      int e = rr & 31, h = rr >> 5;
      int np = c * 256 + h * 32 + e;  // permuted destination row
      _Float16 hi, lo;
      f2h_split(Wq[n * 256 + k], hi, lo);
      Bq[np * 768 + k] = hi;
      Bq[np * 768 + 256 + k] = hi;
      Bq[np * 768 + 512 + k] = lo;
    } else {
      int r = n - 768;
      _Float16 hi, lo;
      f2h_split(Wp[r * 256 + k], hi, lo);
      Bp[r * 768 + k] = hi;
      Bp[r * 768 + 256 + k] = hi;
      Bp[r * 768 + 512 + k] = lo;
    }
    return;
  }
  __shared__ float ps[BALL * 3];
  __shared__ float mean_s[3];
  int ball = blockIdx.x;
  int tid = threadIdx.x;
  if (tid < BALL * 3) ps[tid] = pos[ball * BALL * 3 + tid];
  __syncthreads();
  if (tid < 3) {
    float s = 0.f;
    for (int m = 0; m < BALL; ++m) s += ps[m * 3 + tid];
    mean_s[tid] = s * (1.f / BALL);
  }
  __syncthreads();
  int d = tid;
  float w0 = Wpe[d * 3 + 0], w1 = Wpe[d * 3 + 1], w2 = Wpe[d * 3 + 2];
  float bp = bpe[d];
  float m0 = mean_s[0], m1 = mean_s[1], m2 = mean_s[2];
  for (int m = 0; m < BALL; ++m) {
    int t = ball * BALL + m;
    float r0 = ps[m * 3 + 0] - m0;
    float r1 = ps[m * 3 + 1] - m1;
    float r2 = ps[m * 3 + 2] - m2;
    float val = x[t * DIM + d] + r0 * w0 + r1 * w1 + r2 * w2 + bp;
    _Float16 hi, lo;
    f2h_split(val, hi, lo);
    xcat[t * 512 + d] = hi;
    xcat[t * 512 + 256 + d] = lo;
  }
}

// ---------------------------------------------------------------------------
// Split-fp16 MFMA GEMM core, templated N-width. Tile 128 x (32*NF),
// wave-tile 64 x (16*NF). Async LDS staging + XOR swizzle.
// ---------------------------------------------------------------------------
#define TBK 64

template <int NF, typename AF, typename BF, typename Epi>
__device__ __forceinline__ void gemm_core(AF a_addr, BF b_addr, int m0,
                                          int n0, Epi epi) {
  __shared__ _Float16 As[128 * 64];
  __shared__ _Float16 Bs[32 * NF * 64];
  int tid = threadIdx.x;
  int w = tid >> 6, lane = tid & 63;
  int wm = (w >> 1) * 64, wn = (w & 1) * 16 * NF;
  int l15 = lane & 15, quad = lane >> 4;
  int sw = l15 & 7;
  f32x4 acc[4][NF] = {};
  for (int k0 = 0; k0 < 768; k0 += TBK) {
    int ak0 = (k0 < 512) ? k0 : (k0 - 512);
    if (k0) __syncthreads();
#pragma unroll
    for (int t = 0; t < 4; ++t) {
      int f = tid + 256 * t;  // 0..1023
      int row = f >> 3, sg = (f & 7) ^ (row & 7);
      gld_lds16(&As[f * 8], a_addr(m0 + row, ak0 + sg * 8));
    }
#pragma unroll
    for (int t = 0; t < NF; ++t) {
      int f = tid + 256 * t;  // 0..256*NF-1
      int row = f >> 3, sg = (f & 7) ^ (row & 7);
      gld_lds16(&Bs[f * 8], b_addr(n0 + row, k0 + sg * 8));
    }
    __syncthreads();
#pragma unroll
    for (int kk = 0; kk < TBK; kk += 32) {
      int ls = (kk >> 3) + quad;
      int psg = (ls ^ sw) * 8;
      f16x8 bfr[NF];
#pragma unroll
      for (int nt = 0; nt < NF; ++nt)
        bfr[nt] = *(const f16x8*)&Bs[(wn + nt * 16 + l15) * 64 + psg];
#pragma unroll
      for (int mt = 0; mt < 4; ++mt) {
        f16x8 afr = *(const f16x8*)&As[(wm + mt * 16 + l15) * 64 + psg];
#pragma unroll
        for (int nt = 0; nt < NF; ++nt)
          acc[mt][nt] = __builtin_amdgcn_mfma_f32_16x16x32_f16(
              afr, bfr[nt], acc[mt][nt], 0, 0, 0);
      }
    }
  }
  epi(acc, wm, wn, l15, quad);
}

// K2: qkv GEMM, BN=96 (grid 64x8 = 512 blocks = 2/CU exact).
// Permuted-B cols [q256|k256|v256]; component c uniform per 16-col frag.
__global__ __launch_bounds__(256) void k_qkv_gemm(
    const _Float16* __restrict__ A, const _Float16* __restrict__ B,
    const float* __restrict__ bias, _Float16* __restrict__ qcat,
    _Float16* __restrict__ kmc, _Float16* __restrict__ kv16) {
  int m0 = blockIdx.x * 128, n0 = blockIdx.y * 96;
  gemm_core<3>(
      [=](int r, int k) { return &A[r * 512 + k]; },
      [=](int r, int k) { return &B[r * 768 + k]; }, m0, n0,
      [=](f32x4 (&acc)[4][3], int wm, int wn, int l15, int quad) {
#pragma unroll
        for (int nt = 0; nt < 3; ++nt) {
          int colbase = n0 + wn + nt * 16;  // 16-aligned, frag-uniform
          int c = colbase >> 8;             // 0=q, 1=k, 2=v
          int cc = (colbase & 255) + l15;
          int e = cc & 31, hh = cc >> 5;
          float bv = bias[hh * 96 + e * 3 + c];
#pragma unroll
          for (int mt = 0; mt < 4; ++mt) {
            int rb = m0 + wm + mt * 16;
            if (c == 0) {
#pragma unroll
              for (int r = 0; r < 4; ++r) {
                int row = rb + quad * 4 + r;
                _Float16 hi, lo;
                f2h_split(acc[mt][nt][r] + bv, hi, lo);
                qcat[(hh * NM + row) * 64 + e] = hi;
                qcat[(hh * NM + row) * 64 + 32 + e] = lo;
              }
            } else if (c == 1) {
              float s = 0.f;
#pragma unroll
              for (int r = 0; r < 4; ++r) {
                int row = rb + quad * 4 + r;
                float val = acc[mt][nt][r] + bv;
                kv16[(hh * NM + row) * 64 + e] = (_Float16)val;
                s += acc[mt][nt][r];
              }
              s += __shfl_xor(s, 16);
              s += __shfl_xor(s, 32);
              if (quad == 0) {
                int ball = rb >> 4;
                _Float16 hi, lo;
                f2h_split(s * (1.f / BALL) + bv, hi, lo);
                kmc[(hh * NBALLS + ball) * 64 + e] = hi;
                kmc[(hh * NBALLS + ball) * 64 + 32 + e] = lo;
              }
            } else {
#pragma unroll
              for (int r = 0; r < 4; ++r) {
                int row = rb + quad * 4 + r;
                kv16[(hh * NM + row) * 64 + 32 + e] =
                    (_Float16)(acc[mt][nt][r] + bv);
              }
            }
          }
        }
      });
}

// K5: proj GEMM, BN=64 (grid 64x4 = 256 blocks = 1/CU exact).
__global__ __launch_bounds__(256) void k_proj(
    const _Float16* __restrict__ acat, const _Float16* __restrict__ B,
    const float* __restrict__ bias, float* __restrict__ out) {
  int m0 = blockIdx.x * 128, n0 = blockIdx.y * 64;
  gemm_core<2>(
      [=](int r, int k) {
        int half = k >> 8, hh = (k >> 5) & 7, e0 = k & 31;
        return &acat[((half * NH + hh) * NM + r) * 32 + e0];
      },
      [=](int r, int k) { return &B[r * 768 + k]; }, m0, n0,
      [=](f32x4 (&acc)[4][2], int wm, int wn, int l15, int quad) {
#pragma unroll
        for (int nt = 0; nt < 2; ++nt) {
          int col = n0 + wn + nt * 16 + l15;
          float bv = bias[col];
#pragma unroll
          for (int mt = 0; mt < 4; ++mt) {
#pragma unroll
            for (int r = 0; r < 4; ++r) {
              int row = m0 + wm + mt * 16 + quad * 4 + r;
              out[row * DIM + col] = acc[mt][nt][r] + bv;
            }
          }
        }
      });
}

// ---------------------------------------------------------------------------
// K3: sim+top2 on MFMA. 512-thread blocks, single-stage LDS (whole head's
// kmc = 64 KB staged once, 32 tiles barrier-free). h = bx & 7.
// ---------------------------------------------------------------------------
__global__ __launch_bounds__(512) void k_sim_topk(
    const _Float16* __restrict__ qcat, const _Float16* __restrict__ kmc,
    int2* __restrict__ topk2) {
  __shared__ _Float16 km_s[512 * 64];  // 64 KB
  int tid = threadIdx.x;  // 0..511
  int bx = blockIdx.x;
  int h = bx & 7;
  int wv = tid >> 6, lane = tid & 63;
  int l15 = lane & 15, quad = lane >> 4;
  int sw = l15 & 7;
  int q0 = (bx >> 3) * 128 + wv * 16;

  const _Float16* qr = &qcat[(h * NM + q0 + l15) * 64];
  f16x8 qhi = *(const f16x8*)&qr[quad * 8];
  f16x8 qlo = *(const f16x8*)&qr[32 + quad * 8];

  // stage all 512 balls (4096 granules, 8 per thread)
#pragma unroll
  for (int t = 0; t < 8; ++t) {
    int f = tid + 512 * t;  // 0..4095
    int row = f >> 3, sg = (f & 7) ^ (row & 7);
    gld_lds16(&km_s[f * 8], &kmc[(h * NBALLS + row) * 64 + sg * 8]);
  }
  __syncthreads();

  float v0[4], v1[4];
  int i0[4], i1[4];
#pragma unroll
  for (int r = 0; r < 4; ++r) {
    v0[r] = -1e30f; v1[r] = -1e30f; i0[r] = 0; i1[r] = 0;
  }

#pragma unroll 4
  for (int tile = 0; tile < 32; ++tile) {
    const _Float16* bb = &km_s[(tile * 16 + l15) * 64];
    f16x8 bhi = *(const f16x8*)&bb[(quad ^ sw) * 8];
    f16x8 blo = *(const f16x8*)&bb[((4 + quad) ^ sw) * 8];
    f32x4 acc = {};
    acc = __builtin_amdgcn_mfma_f32_16x16x32_f16(qhi, bhi, acc, 0, 0, 0);
    acc = __builtin_amdgcn_mfma_f32_16x16x32_f16(qlo, bhi, acc, 0, 0, 0);
    acc = __builtin_amdgcn_mfma_f32_16x16x32_f16(qhi, blo, acc, 0, 0, 0);
    int ball = tile * 16 + l15;
#pragma unroll
    for (int r = 0; r < 4; ++r) {
      float s = acc[r];
      bool gt0 = s > v0[r];       // strict: earlier index wins ties
      bool gt1 = s > v1[r];
      float nv1 = gt0 ? v0[r] : (gt1 ? s : v1[r]);
      int ni1 = gt0 ? i0[r] : (gt1 ? ball : i1[r]);
      v0[r] = gt0 ? s : v0[r];
      i0[r] = gt0 ? ball : i0[r];
      v1[r] = nv1;
      i1[r] = ni1;
    }
  }

  // branchless butterfly merge across the 16 lanes of each quad-group
#pragma unroll
  for (int m = 1; m < 16; m <<= 1) {
#pragma unroll
    for (int r = 0; r < 4; ++r) {
      float w0 = __shfl_xor(v0[r], m), w1 = __shfl_xor(v1[r], m);
      int j0 = __shfl_xor(i0[r], m), j1 = __shfl_xor(i1[r], m);
      bool a = w0 > v0[r];            // tie keeps accumulator side
      float c2v = a ? v0[r] : w0;
      int c2i = a ? i0[r] : j0;
      float o2v = a ? w1 : v1[r];
      int o2i = a ? j1 : i1[r];
      v0[r] = a ? w0 : v0[r];
      i0[r] = a ? j0 : i0[r];
      bool b2 = c2v > o2v;
      v1[r] = b2 ? c2v : o2v;
      i1[r] = b2 ? c2i : o2i;
    }
  }
  if (l15 == 0) {
#pragma unroll
    for (int r = 0; r < 4; ++r) {
      int q = q0 + quad * 4 + r;
      topk2[h * NM + q] = make_int2(i0[r], i1[r]);
    }
  }
}

// ---------------------------------------------------------------------------
// K4 v3: minimal-instruction attention. 4 (h,q) waves per block, h = bx&7.
// Lane (j = lane&31, half = lane>>5):
//   - K[j][e0:e0+16] loaded DIRECTLY to regs from kv16 (no LDS for K)
//   - q-hi[e0:e0+16] loaded directly from qcat (broadcast; lo dropped:
//     logit err ~2^-12, well inside tolerance)
//   - QK dot via v_dot2_f32_f16 (8 fdot2 vs 16 cvt + 16 fma)
//   - only V staged in LDS ([j][32], 64B stride; b128 writes conflict-free)
// No block barriers (wave-private LDS slices). Out coalesced to acat.
// ---------------------------------------------------------------------------
__global__ __launch_bounds__(256) void k_attn(
    const _Float16* __restrict__ qcat, const _Float16* __restrict__ kv16,
    const int2* __restrict__ topk2, _Float16* __restrict__ acat) {
  __shared__ _Float16 vs_s[4][32 * 32];
  __shared__ float attw[4][32];
  int wv = threadIdx.x >> 6;
  int lane = threadIdx.x & 63;
  int bx = blockIdx.x;
  int h = bx & 7;
  int t = (bx >> 3) * 4 + wv;
  int j = lane & 31, half = lane >> 5;
  int e0 = half * 16;

  int2 tk = topk2[h * NM + t];

  // K fragment direct to regs
  int ballj = (j < 16) ? tk.x : tk.y;
  const _Float16* krow =
      &kv16[(h * NM + ballj * BALL + (j & 15)) * 64 + e0];
  f16x8 kf0 = *(const f16x8*)krow;
  f16x8 kf1 = *(const f16x8*)(krow + 8);

  // q-hi fragment (uniform across j within each half)
  const _Float16* qrow = &qcat[(h * NM + t) * 64 + e0];
  f16x8 qf0 = *(const f16x8*)qrow;
  f16x8 qf1 = *(const f16x8*)(qrow + 8);

  // stage V: granules vi = lane, lane+64; row = vi>>2, seg = vi&3
#pragma unroll
  for (int i = 0; i < 2; ++i) {
    int vi = lane + 64 * i;  // 0..127
    int row = vi >> 2, s = vi & 3;
    int ball = (row < 16) ? tk.x : tk.y;
    *(uint4*)&vs_s[wv][row * 32 + s * 8] =
        *(const uint4*)&kv16[(h * NM + ball * BALL + (row & 15)) * 64 + 32 +
                             s * 8];
  }

  // QK dot via fdot2
  float partial = 0.f;
  {
    const f16x2* qa = (const f16x2*)&qf0;
    const f16x2* ka = (const f16x2*)&kf0;
    const f16x2* qb = (const f16x2*)&qf1;
    const f16x2* kb = (const f16x2*)&kf1;
#pragma unroll
    for (int p = 0; p < 4; ++p) partial = FDOT2(qa[p], ka[p], partial);
#pragma unroll
    for (int p = 0; p < 4; ++p) partial = FDOT2(qb[p], kb[p], partial);
  }
  partial += __shfl_xor(partial, 32);
  float logit = partial * 0.17677669529663687f;  // 1/sqrt(32)
  float mx = logit;
#pragma unroll
  for (int mk = 1; mk <= 16; mk <<= 1) mx = fmaxf(mx, __shfl_xor(mx, mk));
  float pexp = __expf(logit - mx);
  float sum = pexp;
#pragma unroll
  for (int mk = 1; mk <= 16; mk <<= 1) sum += __shfl_xor(sum, mk);
  float attn = pexp / sum;
  if (lane < 32) attw[wv][j] = attn;

  // PV: lane e sums its half's 16 keys (attw reads are LDS broadcasts)
  int e = j, j0 = half * 16;
  float po = 0.f;
#pragma unroll
  for (int jj = 0; jj < 16; ++jj)
    po += attw[wv][j0 + jj] * (float)vs_s[wv][(j0 + jj) * 32 + e];
  po += __shfl_xor(po, 32);
  if (lane < 32) {
    _Float16 hi, lo;
    f2h_split(po, hi, lo);
    acat[(h * NM + t) * 32 + e] = hi;               // half 0
    acat[((NH + h) * NM + t) * 32 + e] = lo;        // half 1
  }
}

extern "C" void kernel_launch(void* const* d_in, const int* in_sizes, int n_in,
                              void* d_out, int out_size, void* d_ws,
                              size_t ws_size, hipStream_t stream) {
  const float* x = (const float*)d_in[0];
  const float* pos = (const float*)d_in[1];
  const float* Wqkv = (const float*)d_in[2];
  const float* bqkv = (const float*)d_in[3];
  const float* Wpe = (const float*)d_in[4];
  const float* bpe = (const float*)d_in[5];
  const float* Wproj = (const float*)d_in[6];
  const float* bproj = (const float*)d_in[7];
  float* out = (float*)d_out;

  _Float16* kv16 = (_Float16*)d_ws;                   // 8 MB
  _Float16* qcat = kv16 + NH * NM * 64;               // 8 MB
  _Float16* kmc = qcat + NH * NM * 64;                // 512 KB
  int2* topk2 = (int2*)(kmc + NH * NBALLS * 64);      // 512 KB
  _Float16* xcat = (_Float16*)(topk2 + NH * NM);      // 8 MB
  _Float16* acat = xcat + NM * 512;                   // 8 MB
  _Float16* Bq = acat + 2 * NH * NM * 32;             // 1.2 MB
  _Float16* Bp = Bq + 768 * 768;                      // 0.4 MB

  k_prep<<<NBALLS + 1024, 256, 0, stream>>>(x, pos, Wpe, bpe, xcat, Wqkv,
                                            Wproj, Bq, Bp);
  k_qkv_gemm<<<dim3(NM / 128, 768 / 96), 256, 0, stream>>>(xcat, Bq, bqkv,
                                                           qcat, kmc, kv16);
  k_sim_topk<<<NM / 128 * NH, 512, 0, stream>>>(qcat, kmc, topk2);
  k_attn<<<NH * NM / 4, 256, 0, stream>>>(qcat, kv16, topk2, acat);
  k_proj<<<dim3(NM / 128, DIM / 64), 256, 0, stream>>>(acat, Bp, bproj, out);
}

// Round 17
// 144.104 us; speedup vs baseline: 1.0489x; 1.0489x over previous
//
#include <hip/hip_runtime.h>

#define DIM 256
#define NH 8
#define HE 32          // head dim E
#define BALL 16        // ball size M
#define NBALLS 512
#define NM 8192

typedef _Float16 f16x8 __attribute__((ext_vector_type(8)));
typedef float f32x4 __attribute__((ext_vector_type(4)));

// fp16 2-term split: x = hi + lo, residual ~2^-24 |x| (fp32-quality)
__device__ __forceinline__ void f2h_split(float val, _Float16& hi,
                                          _Float16& lo) {
  hi = (_Float16)val;
  lo = (_Float16)(val - (float)hi);
}

// async global->LDS, 16B per lane; LDS dest = wave-uniform base + lane*16
__device__ __forceinline__ void gld_lds16(_Float16* lds, const _Float16* g) {
  __builtin_amdgcn_global_load_lds(
      (const __attribute__((address_space(1))) unsigned int*)g,
      (__attribute__((address_space(3))) unsigned int*)lds, 16, 0, 0);
}

// ---------------------------------------------------------------------------
// K1 (fused): blocks [0,512): posembed -> xcat[t][hi256|lo256]
//   blocks [512,1536): weight split -> Bq/Bp concatenated-K fp16.
//   Bq rows PERMUTED component-major: row n' = c*256 + h*32 + e.
// ---------------------------------------------------------------------------
__global__ __launch_bounds__(256) void k_prep(
    const float* __restrict__ x, const float* __restrict__ pos,
    const float* __restrict__ Wpe, const float* __restrict__ bpe,
    _Float16* __restrict__ xcat, const float* __restrict__ Wq,
    const float* __restrict__ Wp, _Float16* __restrict__ Bq,
    _Float16* __restrict__ Bp) {
  if (blockIdx.x >= NBALLS) {
    int n = blockIdx.x - NBALLS;  // 0..1023
    int k = threadIdx.x;
    if (n < 768) {
      int c = n % 3, rr = n / 3;
      int e = rr & 31, h = rr >> 5;
      int np = c * 256 + h * 32 + e;  // permuted destination row
      _Float16 hi, lo;
      f2h_split(Wq[n * 256 + k], hi, lo);
      Bq[np * 768 + k] = hi;
      Bq[np * 768 + 256 + k] = hi;
      Bq[np * 768 + 512 + k] = lo;
    } else {
      int r = n - 768;
      _Float16 hi, lo;
      f2h_split(Wp[r * 256 + k], hi, lo);
      Bp[r * 768 + k] = hi;
      Bp[r * 768 + 256 + k] = hi;
      Bp[r * 768 + 512 + k] = lo;
    }
    return;
  }
  __shared__ float ps[BALL * 3];
  __shared__ float mean_s[3];
  int ball = blockIdx.x;
  int tid = threadIdx.x;
  if (tid < BALL * 3) ps[tid] = pos[ball * BALL * 3 + tid];
  __syncthreads();
  if (tid < 3) {
    float s = 0.f;
    for (int m = 0; m < BALL; ++m) s += ps[m * 3 + tid];
    mean_s[tid] = s * (1.f / BALL);
  }
  __syncthreads();
  int d = tid;
  float w0 = Wpe[d * 3 + 0], w1 = Wpe[d * 3 + 1], w2 = Wpe[d * 3 + 2];
  float bp = bpe[d];
  float m0 = mean_s[0], m1 = mean_s[1], m2 = mean_s[2];
  for (int m = 0; m < BALL; ++m) {
    int t = ball * BALL + m;
    float r0 = ps[m * 3 + 0] - m0;
    float r1 = ps[m * 3 + 1] - m1;
    float r2 = ps[m * 3 + 2] - m2;
    float val = x[t * DIM + d] + r0 * w0 + r1 * w1 + r2 * w2 + bp;
    _Float16 hi, lo;
    f2h_split(val, hi, lo);
    xcat[t * 512 + d] = hi;
    xcat[t * 512 + 256 + d] = lo;
  }
}

// ---------------------------------------------------------------------------
// Split-fp16 MFMA GEMM core, async LDS staging + XOR swizzle.
// Tile 128x64, BK=64, wave-tile 64x32 = 4x2 mfma_f32_16x16x32_f16.
// Tile-level epilogue: epi(acc, wm, wn, l15, quad).
// ---------------------------------------------------------------------------
#define TBK 64

template <typename AF, typename BF, typename Epi>
__device__ __forceinline__ void gemm_core(AF a_addr, BF b_addr, int m0,
                                          int n0, Epi epi) {
  __shared__ _Float16 As[128 * 64];
  __shared__ _Float16 Bs[64 * 64];
  int tid = threadIdx.x;
  int w = tid >> 6, lane = tid & 63;
  int wm = (w >> 1) * 64, wn = (w & 1) * 32;
  int l15 = lane & 15, quad = lane >> 4;
  int sw = l15 & 7;
  f32x4 acc[4][2] = {};
  for (int k0 = 0; k0 < 768; k0 += TBK) {
    int ak0 = (k0 < 512) ? k0 : (k0 - 512);
    if (k0) __syncthreads();
#pragma unroll
    for (int t = 0; t < 4; ++t) {
      int f = tid + 256 * t;  // 0..1023
      int row = f >> 3, sg = (f & 7) ^ (row & 7);
      gld_lds16(&As[f * 8], a_addr(m0 + row, ak0 + sg * 8));
    }
#pragma unroll
    for (int t = 0; t < 2; ++t) {
      int f = tid + 256 * t;  // 0..511
      int row = f >> 3, sg = (f & 7) ^ (row & 7);
      gld_lds16(&Bs[f * 8], b_addr(n0 + row, k0 + sg * 8));
    }
    __syncthreads();
#pragma unroll
    for (int kk = 0; kk < TBK; kk += 32) {
      int ls = (kk >> 3) + quad;
      int psg = (ls ^ sw) * 8;
      f16x8 bfr0 = *(const f16x8*)&Bs[(wn + l15) * 64 + psg];
      f16x8 bfr1 = *(const f16x8*)&Bs[(wn + 16 + l15) * 64 + psg];
#pragma unroll
      for (int mt = 0; mt < 4; ++mt) {
        f16x8 afr = *(const f16x8*)&As[(wm + mt * 16 + l15) * 64 + psg];
        acc[mt][0] = __builtin_amdgcn_mfma_f32_16x16x32_f16(afr, bfr0,
                                                            acc[mt][0], 0, 0,
                                                            0);
        acc[mt][1] = __builtin_amdgcn_mfma_f32_16x16x32_f16(afr, bfr1,
                                                            acc[mt][1], 0, 0,
                                                            0);
      }
    }
  }
  epi(acc, wm, wn, l15, quad);
}

// K2: qkv GEMM with permuted-B output cols [q256|k256|v256].
// q -> qcat split-fp16; k -> kv16[..e] + fused kmean -> kmc; v -> kv16[..32+e]
__global__ __launch_bounds__(256) void k_qkv_gemm(
    const _Float16* __restrict__ A, const _Float16* __restrict__ B,
    const float* __restrict__ bias, _Float16* __restrict__ qcat,
    _Float16* __restrict__ kmc, _Float16* __restrict__ kv16) {
  int m0 = blockIdx.x * 128, n0 = blockIdx.y * 64;
  int c = n0 >> 8;  // block-uniform component: 0=q, 1=k, 2=v
  gemm_core(
      [=](int r, int k) { return &A[r * 512 + k]; },
      [=](int r, int k) { return &B[r * 768 + k]; }, m0, n0,
      [=](f32x4 (&acc)[4][2], int wm, int wn, int l15, int quad) {
#pragma unroll
        for (int nt = 0; nt < 2; ++nt) {
          int col = n0 + wn + nt * 16 + l15;
          int cc = col & 255;
          int e = cc & 31, h = cc >> 5;
          float bv = bias[h * 96 + e * 3 + c];
#pragma unroll
          for (int mt = 0; mt < 4; ++mt) {
            int rb = m0 + wm + mt * 16;
            if (c == 0) {
#pragma unroll
              for (int r = 0; r < 4; ++r) {
                int row = rb + quad * 4 + r;
                _Float16 hi, lo;
                f2h_split(acc[mt][nt][r] + bv, hi, lo);
                qcat[(h * NM + row) * 64 + e] = hi;
                qcat[(h * NM + row) * 64 + 32 + e] = lo;
              }
            } else if (c == 1) {
              float s = 0.f;
#pragma unroll
              for (int r = 0; r < 4; ++r) {
                int row = rb + quad * 4 + r;
                float val = acc[mt][nt][r] + bv;
                kv16[(h * NM + row) * 64 + e] = (_Float16)val;
                s += acc[mt][nt][r];
              }
              s += __shfl_xor(s, 16);
              s += __shfl_xor(s, 32);
              if (quad == 0) {
                int ball = rb >> 4;
                _Float16 hi, lo;
                f2h_split(s * (1.f / BALL) + bv, hi, lo);
                kmc[(h * NBALLS + ball) * 64 + e] = hi;
                kmc[(h * NBALLS + ball) * 64 + 32 + e] = lo;
              }
            } else {
#pragma unroll
              for (int r = 0; r < 4; ++r) {
                int row = rb + quad * 4 + r;
                kv16[(h * NM + row) * 64 + 32 + e] =
                    (_Float16)(acc[mt][nt][r] + bv);
              }
            }
          }
        }
      });
}

// K5: proj GEMM. A = acat in [half][h][t][32] layout (coalesced attn writes)
__global__ __launch_bounds__(256) void k_proj(
    const _Float16* __restrict__ acat, const _Float16* __restrict__ B,
    const float* __restrict__ bias, float* __restrict__ out) {
  int m0 = blockIdx.x * 128, n0 = blockIdx.y * 64;
  gemm_core(
      [=](int r, int k) {
        int half = k >> 8, hh = (k >> 5) & 7, e0 = k & 31;
        return &acat[((half * NH + hh) * NM + r) * 32 + e0];
      },
      [=](int r, int k) { return &B[r * 768 + k]; }, m0, n0,
      [=](f32x4 (&acc)[4][2], int wm, int wn, int l15, int quad) {
#pragma unroll
        for (int nt = 0; nt < 2; ++nt) {
          int col = n0 + wn + nt * 16 + l15;
          float bv = bias[col];
#pragma unroll
          for (int mt = 0; mt < 4; ++mt) {
#pragma unroll
            for (int r = 0; r < 4; ++r) {
              int row = m0 + wm + mt * 16 + quad * 4 + r;
              out[row * DIM + col] = acc[mt][nt][r] + bv;
            }
          }
        }
      });
}

// ---------------------------------------------------------------------------
// K3: sim+top2 on MFMA, branchless top-2, 512-thread blocks.
// ---------------------------------------------------------------------------
__global__ __launch_bounds__(512) void k_sim_topk(
    const _Float16* __restrict__ qcat, const _Float16* __restrict__ kmc,
    int2* __restrict__ topk2) {
  __shared__ _Float16 km_s[128 * 64];
  int tid = threadIdx.x;  // 0..511
  int h = blockIdx.y;
  int wv = tid >> 6, lane = tid & 63;
  int l15 = lane & 15, quad = lane >> 4;
  int sw = l15 & 7;
  int q0 = blockIdx.x * 128 + wv * 16;

  const _Float16* qr = &qcat[(h * NM + q0 + l15) * 64];
  f16x8 qhi = *(const f16x8*)&qr[quad * 8];
  f16x8 qlo = *(const f16x8*)&qr[32 + quad * 8];

  float v0[4], v1[4];
  int i0[4], i1[4];
#pragma unroll
  for (int r = 0; r < 4; ++r) {
    v0[r] = -1e30f; v1[r] = -1e30f; i0[r] = 0; i1[r] = 0;
  }

  for (int ch = 0; ch < 4; ++ch) {
    if (ch) __syncthreads();
#pragma unroll
    for (int t = 0; t < 2; ++t) {
      int f = tid + 512 * t;  // 0..1023
      int row = f >> 3, sg = (f & 7) ^ (row & 7);
      gld_lds16(&km_s[f * 8],
                &kmc[(h * NBALLS + ch * 128 + row) * 64 + sg * 8]);
    }
    __syncthreads();

#pragma unroll
    for (int tile = 0; tile < 8; ++tile) {
      const _Float16* bb = &km_s[(tile * 16 + l15) * 64];
      f16x8 bhi = *(const f16x8*)&bb[(quad ^ sw) * 8];
      f16x8 blo = *(const f16x8*)&bb[((4 + quad) ^ sw) * 8];
      f32x4 acc = {};
      acc = __builtin_amdgcn_mfma_f32_16x16x32_f16(qhi, bhi, acc, 0, 0, 0);
      acc = __builtin_amdgcn_mfma_f32_16x16x32_f16(qlo, bhi, acc, 0, 0, 0);
      acc = __builtin_amdgcn_mfma_f32_16x16x32_f16(qhi, blo, acc, 0, 0, 0);
      int ball = ch * 128 + tile * 16 + l15;
#pragma unroll
      for (int r = 0; r < 4; ++r) {
        float s = acc[r];
        bool gt0 = s > v0[r];       // strict: earlier index wins ties
        bool gt1 = s > v1[r];
        float nv1 = gt0 ? v0[r] : (gt1 ? s : v1[r]);
        int ni1 = gt0 ? i0[r] : (gt1 ? ball : i1[r]);
        v0[r] = gt0 ? s : v0[r];
        i0[r] = gt0 ? ball : i0[r];
        v1[r] = nv1;
        i1[r] = ni1;
      }
    }
  }

#pragma unroll
  for (int m = 1; m < 16; m <<= 1) {
#pragma unroll
    for (int r = 0; r < 4; ++r) {
      float w0 = __shfl_xor(v0[r], m), w1 = __shfl_xor(v1[r], m);
      int j0 = __shfl_xor(i0[r], m), j1 = __shfl_xor(i1[r], m);
      bool a = w0 > v0[r];            // tie keeps accumulator side
      float c2v = a ? v0[r] : w0;
      int c2i = a ? i0[r] : j0;
      float o2v = a ? w1 : v1[r];
      int o2i = a ? j1 : i1[r];
      v0[r] = a ? w0 : v0[r];
      i0[r] = a ? j0 : i0[r];
      bool b2 = c2v > o2v;
      v1[r] = b2 ? c2v : o2v;
      i1[r] = b2 ? c2i : o2i;
    }
  }
  if (l15 == 0) {
#pragma unroll
    for (int r = 0; r < 4; ++r) {
      int q = q0 + quad * 4 + r;
      topk2[h * NM + q] = make_int2(i0[r], i1[r]);
    }
  }
}

// ---------------------------------------------------------------------------
// K4: fp16 interleaved K/V gather, 4 (h,q) waves per block. Output written
// coalesced to acat [half][h][t][32].
// ---------------------------------------------------------------------------
__global__ __launch_bounds__(256) void k_attn(
    const _Float16* __restrict__ qcat, const _Float16* __restrict__ kv16,
    const int2* __restrict__ topk2, _Float16* __restrict__ acat) {
  __shared__ _Float16 kv_s[4][32 * 72];
  __shared__ float q_s[4][HE];
  __shared__ float attw[4][32];
  int wv = threadIdx.x >> 6;
  int tid = threadIdx.x & 63;
  int idx = blockIdx.x * 4 + wv;
  int h = idx >> 13, t = idx & (NM - 1);

  int2 tk = topk2[h * NM + t];

  if (tid < HE) {
    const _Float16* qr = &qcat[(h * NM + t) * 64];
    q_s[wv][tid] = (float)qr[tid] + (float)qr[32 + tid];
  }
#pragma unroll
  for (int i = 0; i < 4; ++i) {
    int g = tid + 64 * i;            // 0..255
    int j = g >> 3, seg = g & 7;     // token row j, 16B segment
    int ball = (j < 16) ? tk.x : tk.y;
    int m = j & 15;
    *(uint4*)&kv_s[wv][j * 72 + seg * 8] =
        *(const uint4*)&kv16[(h * NM + ball * BALL + m) * 64 + seg * 8];
  }
  __syncthreads();

  int j = tid & 31, half = tid >> 5;
  int e0 = half * 16;
  float partial = 0.f;
  {
    f16x8 ka = *(const f16x8*)&kv_s[wv][j * 72 + e0];
    f16x8 kb = *(const f16x8*)&kv_s[wv][j * 72 + e0 + 8];
#pragma unroll
    for (int e = 0; e < 8; ++e) {
      partial += q_s[wv][e0 + e] * (float)ka[e];
      partial += q_s[wv][e0 + 8 + e] * (float)kb[e];
    }
  }
  partial += __shfl_xor(partial, 32);
  float logit = partial * 0.17677669529663687f;  // 1/sqrt(32)
  float mx = logit;
#pragma unroll
  for (int mk = 1; mk <= 16; mk <<= 1) mx = fmaxf(mx, __shfl_xor(mx, mk));
  float pexp = __expf(logit - mx);
  float sum = pexp;
#pragma unroll
  for (int mk = 1; mk <= 16; mk <<= 1) sum += __shfl_xor(sum, mk);
  float attn = pexp / sum;
  if (tid < 32) attw[wv][j] = attn;
  __syncthreads();

  int e = tid & 31, j0 = half * 16;
  float po = 0.f;
#pragma unroll
  for (int jj = 0; jj < 16; ++jj)
    po += attw[wv][j0 + jj] * (float)kv_s[wv][(j0 + jj) * 72 + 32 + e];
  po += __shfl_xor(po, 32);
  if (tid < 32) {
    _Float16 hi, lo;
    f2h_split(po, hi, lo);
    acat[(h * NM + t) * 32 + e] = hi;               // half 0
    acat[((NH + h) * NM + t) * 32 + e] = lo;        // half 1
  }
}

extern "C" void kernel_launch(void* const* d_in, const int* in_sizes, int n_in,
                              void* d_out, int out_size, void* d_ws,
                              size_t ws_size, hipStream_t stream) {
  const float* x = (const float*)d_in[0];
  const float* pos = (const float*)d_in[1];
  const float* Wqkv = (const float*)d_in[2];
  const float* bqkv = (const float*)d_in[3];
  const float* Wpe = (const float*)d_in[4];
  const float* bpe = (const float*)d_in[5];
  const float* Wproj = (const float*)d_in[6];
  const float* bproj = (const float*)d_in[7];
  float* out = (float*)d_out;

  _Float16* kv16 = (_Float16*)d_ws;                   // 8 MB
  _Float16* qcat = kv16 + NH * NM * 64;               // 8 MB
  _Float16* kmc = qcat + NH * NM * 64;                // 512 KB
  int2* topk2 = (int2*)(kmc + NH * NBALLS * 64);      // 512 KB
  _Float16* xcat = (_Float16*)(topk2 + NH * NM);      // 8 MB
  _Float16* acat = xcat + NM * 512;                   // 8 MB
  _Float16* Bq = acat + 2 * NH * NM * 32;             // 1.2 MB
  _Float16* Bp = Bq + 768 * 768;                      // 0.4 MB

  k_prep<<<NBALLS + 1024, 256, 0, stream>>>(x, pos, Wpe, bpe, xcat, Wqkv,
                                            Wproj, Bq, Bp);
  k_qkv_gemm<<<dim3(NM / 128, 768 / 64), 256, 0, stream>>>(xcat, Bq, bqkv,
                                                           qcat, kmc, kv16);
  k_sim_topk<<<dim3(NM / 128, NH), 512, 0, stream>>>(qcat, kmc, topk2);
  k_attn<<<NH * NM / 4, 256, 0, stream>>>(qcat, kv16, topk2, acat);
  k_proj<<<dim3(NM / 128, DIM / 64), 256, 0, stream>>>(acat, Bp, bproj, out);
}